// Round 4
// baseline (14686.020 us; speedup 1.0000x reference)
//
#include <hip/hip_runtime.h>
#include <hip/hip_cooperative_groups.h>

#define TT 4096

typedef __attribute__((ext_vector_type(4))) float f4;
typedef __attribute__((ext_vector_type(2))) unsigned int u2;

// ws layout (float offsets):
//   M     @ 0        : 2048*64 = 131072   (W_in @ C)
//   wtil  @ 131072   : 64                 (C^T @ dense_W[:64])
//   yp    @ 131200   : 4096*128 = 524288  (per-WG dense partials, [t][wg])
//   pairs @ 655488   : 2 slots * 2048 * (u32 tag, f32 h) = 8192 floats

__global__ void esn_prep(const float* __restrict__ C,
                         const float* __restrict__ Win,
                         const float* __restrict__ dW,
                         float* __restrict__ M,
                         float* __restrict__ wtil,
                         u2* __restrict__ pairs) {
  __shared__ float s[64];
  const int b = blockIdx.x, i = threadIdx.x;
  if (b < 2048) {
    s[i] = Win[b * 64 + i];
    __syncthreads();
    float acc = 0.f;
#pragma unroll 16
    for (int d = 0; d < 64; ++d) acc += s[d] * C[d * 64 + i];
    M[b * 64 + i] = acc;
  } else if (b == 2048) {
    s[i] = dW[i];
    __syncthreads();
    float acc = 0.f;
    for (int d = 0; d < 64; ++d) acc += s[d] * C[d * 64 + i];
    wtil[i] = acc;
  } else {
    // zero both pair slots: tag=0 matches step 0's expectation, h=0
    u2 z; z.x = 0u; z.y = 0u;
    for (int k = i; k < 2 * 2048; k += 64) pairs[k] = z;
  }
}

// 128 WGs x 1024 threads. WG owns 16 rows; wave owns 1 row; lane owns cols
// {4*lane + 256*k : k<8}. Weights PINNED in VGPRs via asm value barrier
// (prevents the allocator from sinking the loads back into the t-loop,
// which round 3 showed costs ~20x W refetch = 321 MB HBM).
__global__ __launch_bounds__(1024, 4) void esn_recur(
    const float* __restrict__ X, const float* __restrict__ M,
    const float* __restrict__ W, const float* __restrict__ dW,
    u2* __restrict__ pairs, float* __restrict__ yp) {
  __shared__ float shh[2048];
  __shared__ float ps[16];
  const int tid = threadIdx.x;
  const int lane = tid & 63;
  const int wave = tid >> 6;
  const int row = (int)blockIdx.x * 16 + wave;
  const float m = M[row * 64 + lane];
  const float dwv = dW[64 + row];
  const float* wp = W + (size_t)row * 2048 + (lane << 2);
  f4 w0 = *(const f4*)(wp);
  f4 w1 = *(const f4*)(wp + 256);
  f4 w2 = *(const f4*)(wp + 512);
  f4 w3 = *(const f4*)(wp + 768);
  f4 w4 = *(const f4*)(wp + 1024);
  f4 w5 = *(const f4*)(wp + 1280);
  f4 w6 = *(const f4*)(wp + 1536);
  f4 w7 = *(const f4*)(wp + 1792);
  // value barrier: weights become asm-defined -> not rematerializable
  asm volatile("" : "+v"(w0), "+v"(w1), "+v"(w2), "+v"(w3),
                    "+v"(w4), "+v"(w5), "+v"(w6), "+v"(w7));

  for (int t = 0; t < TT; ++t) {
    // prefetch x_t (read-only, L1-broadcast across waves)
    const float xv = X[t * 64 + lane];
    // ---- spin until both owned pairs of slot (t-1)&1 carry tag t ----
    const unsigned tg = (unsigned)t;
    const u2* base = pairs + (((t + 1) & 1) << 11);
    const u2* a0 = base + tid;
    const u2* a1 = base + tid + 1024;
    u2 p0, p1;
    for (;;) {
      asm volatile(
          "global_load_dwordx2 %0, %2, off sc0 sc1\n\t"
          "global_load_dwordx2 %1, %3, off sc0 sc1\n\t"
          "s_waitcnt vmcnt(0)"
          : "=&v"(p0), "=&v"(p1)
          : "v"(a0), "v"(a1)
          : "memory");
      if (p0.x == tg && p1.x == tg) break;
      __builtin_amdgcn_s_sleep(1);
    }
    shh[tid] = __uint_as_float(p0.y);
    shh[tid + 1024] = __uint_as_float(p1.y);
    __syncthreads();
    // ---- one row per wave: dot(W_row, h) + dot(M_row, x) ----
    const float* hp = shh + (lane << 2);
    f4 h0 = *(const f4*)(hp);
    f4 h1 = *(const f4*)(hp + 256);
    f4 h2 = *(const f4*)(hp + 512);
    f4 h3 = *(const f4*)(hp + 768);
    f4 h4 = *(const f4*)(hp + 1024);
    f4 h5 = *(const f4*)(hp + 1280);
    f4 h6 = *(const f4*)(hp + 1536);
    f4 h7 = *(const f4*)(hp + 1792);
    float a = m * xv;
    a += w0.x * h0.x + w0.y * h0.y + w0.z * h0.z + w0.w * h0.w;
    a += w1.x * h1.x + w1.y * h1.y + w1.z * h1.z + w1.w * h1.w;
    a += w2.x * h2.x + w2.y * h2.y + w2.z * h2.z + w2.w * h2.w;
    a += w3.x * h3.x + w3.y * h3.y + w3.z * h3.z + w3.w * h3.w;
    a += w4.x * h4.x + w4.y * h4.y + w4.z * h4.z + w4.w * h4.w;
    a += w5.x * h5.x + w5.y * h5.y + w5.z * h5.z + w5.w * h5.w;
    a += w6.x * h6.x + w6.y * h6.y + w6.z * h6.z + w6.w * h6.w;
    a += w7.x * h7.x + w7.y * h7.y + w7.z * h7.z + w7.w * h7.w;
#pragma unroll
    for (int off = 32; off; off >>= 1) a += __shfl_xor(a, off, 64);
    if (lane == 0) {
      const float h = tanhf(a);
      u2 pv;
      pv.x = tg + 1u;
      pv.y = __float_as_uint(h);
      u2* dst = pairs + ((t & 1) << 11) + row;
      asm volatile("global_store_dwordx2 %0, %1, off sc0 sc1"
                   :: "v"(dst), "v"(pv) : "memory");
      ps[wave] = dwv * h;
    }
    __syncthreads();
    if (tid == 0) {
      float s = 0.f;
#pragma unroll
      for (int wv = 0; wv < 16; ++wv) s += ps[wv];
      yp[t * 128 + blockIdx.x] = s;
    }
  }
}

__global__ void esn_out(const float* __restrict__ X,
                        const float* __restrict__ wtil,
                        const float* __restrict__ yp,
                        const float* __restrict__ bptr,
                        float* __restrict__ out) {
  const int tid = threadIdx.x;
  const int lane = tid & 63;
  const int wave = tid >> 6;
  const int t = blockIdx.x * 4 + wave;
  float v = wtil[lane] * X[t * 64 + lane] + yp[t * 128 + lane] + yp[t * 128 + 64 + lane];
#pragma unroll
  for (int off = 32; off; off >>= 1) v += __shfl_xor(v, off, 64);
  if (lane == 0) out[t] = v + bptr[0];
}

extern "C" void kernel_launch(void* const* d_in, const int* in_sizes, int n_in,
                              void* d_out, int out_size, void* d_ws, size_t ws_size,
                              hipStream_t stream) {
  const float* X   = (const float*)d_in[0];
  const float* C   = (const float*)d_in[1];
  const float* Win = (const float*)d_in[2];
  const float* W   = (const float*)d_in[3];
  const float* dW  = (const float*)d_in[4];
  const float* db  = (const float*)d_in[5];
  float* ws   = (float*)d_ws;
  float* M    = ws;
  float* wtil = ws + 131072;
  float* yp   = ws + 131200;
  u2*    pairs = (u2*)(ws + 655488);

  esn_prep<<<2050, 64, 0, stream>>>(C, Win, dW, M, wtil, pairs);

  void* args[] = {(void*)&X, (void*)&M, (void*)&W, (void*)&dW,
                  (void*)&pairs, (void*)&yp};
  hipLaunchCooperativeKernel(reinterpret_cast<void*>(&esn_recur), dim3(128),
                             dim3(1024), args, 0, stream);

  esn_out<<<1024, 256, 0, stream>>>(X, wtil, yp, db, (float*)d_out);
}

// Round 5
// 14207.538 us; speedup vs baseline: 1.0337x; 1.0337x over previous
//
#include <hip/hip_runtime.h>
#include <hip/hip_cooperative_groups.h>

#define TT 4096

typedef __attribute__((ext_vector_type(4))) float f4;
typedef __attribute__((ext_vector_type(2))) unsigned int u2;

// ws layout (float offsets):
//   M     @ 0        : 2048*64 = 131072   (W_in @ C)
//   wtil  @ 131072   : 64                 (C^T @ dense_W[:64])
//   yp    @ 131200   : 4096*128 = 524288  (per-WG dense partials, [t][wg])
//   pairs @ 655488   : 2 slots * 2048 * (u32 tag, f32 h) = 8192 floats

__global__ void esn_prep(const float* __restrict__ C,
                         const float* __restrict__ Win,
                         const float* __restrict__ dW,
                         float* __restrict__ M,
                         float* __restrict__ wtil,
                         u2* __restrict__ pairs) {
  __shared__ float s[64];
  const int b = blockIdx.x, i = threadIdx.x;
  if (b < 2048) {
    s[i] = Win[b * 64 + i];
    __syncthreads();
    float acc = 0.f;
#pragma unroll 16
    for (int d = 0; d < 64; ++d) acc += s[d] * C[d * 64 + i];
    M[b * 64 + i] = acc;
  } else if (b == 2048) {
    s[i] = dW[i];
    __syncthreads();
    float acc = 0.f;
    for (int d = 0; d < 64; ++d) acc += s[d] * C[d * 64 + i];
    wtil[i] = acc;
  } else {
    // zero both pair slots: tag=0 matches step 0's expectation, h=0
    u2 z; z.x = 0u; z.y = 0u;
    for (int k = i; k < 2 * 2048; k += 64) pairs[k] = z;
  }
}

// Call-free tanh: tanh(x) = 1 - 2/(exp(2x)+1), exp via v_exp_f32, rcp via
// v_rcp_f32. No __ocml_* call -> no call-ABI register clobber in the loop.
__device__ __forceinline__ float fast_tanh(float x) {
  const float e = __builtin_amdgcn_exp2f(x * 2.8853900817779268f);  // exp(2x)
  return 1.0f - 2.0f * __builtin_amdgcn_rcpf(e + 1.0f);
}

// 128 WGs x 1024 threads. WG owns 16 rows; wave owns 1 row; lane owns cols
// {4*lane + 256*k : k<8}. Weights pinned in VGPRs via asm value barrier;
// with the tanhf libcall removed the allocator has no reason to spill them.
__global__ __launch_bounds__(1024, 4) void esn_recur(
    const float* __restrict__ X, const float* __restrict__ M,
    const float* __restrict__ W, const float* __restrict__ dW,
    u2* __restrict__ pairs, float* __restrict__ yp) {
  __shared__ float shh[2048];
  __shared__ float ps[16];
  const int tid = threadIdx.x;
  const int lane = tid & 63;
  const int wave = tid >> 6;
  const int row = (int)blockIdx.x * 16 + wave;
  const float m = M[row * 64 + lane];
  const float dwv = dW[64 + row];
  const float* wp = W + (size_t)row * 2048 + (lane << 2);
  f4 w0 = *(const f4*)(wp);
  f4 w1 = *(const f4*)(wp + 256);
  f4 w2 = *(const f4*)(wp + 512);
  f4 w3 = *(const f4*)(wp + 768);
  f4 w4 = *(const f4*)(wp + 1024);
  f4 w5 = *(const f4*)(wp + 1280);
  f4 w6 = *(const f4*)(wp + 1536);
  f4 w7 = *(const f4*)(wp + 1792);
  // value barrier: weights become asm-defined -> not rematerializable
  asm volatile("" : "+v"(w0), "+v"(w1), "+v"(w2), "+v"(w3),
                    "+v"(w4), "+v"(w5), "+v"(w6), "+v"(w7));

  for (int t = 0; t < TT; ++t) {
    // prefetch x_t (read-only, L1-broadcast across waves)
    const float xv = X[t * 64 + lane];
    // ---- spin until both owned pairs of slot (t-1)&1 carry tag t ----
    const unsigned tg = (unsigned)t;
    const u2* base = pairs + (((t + 1) & 1) << 11);
    const u2* a0 = base + tid;
    const u2* a1 = base + tid + 1024;
    u2 p0, p1;
    for (;;) {
      asm volatile(
          "global_load_dwordx2 %0, %2, off sc0 sc1\n\t"
          "global_load_dwordx2 %1, %3, off sc0 sc1\n\t"
          "s_waitcnt vmcnt(0)"
          : "=&v"(p0), "=&v"(p1)
          : "v"(a0), "v"(a1)
          : "memory");
      if (p0.x == tg && p1.x == tg) break;
      __builtin_amdgcn_s_sleep(1);
    }
    shh[tid] = __uint_as_float(p0.y);
    shh[tid + 1024] = __uint_as_float(p1.y);
    __syncthreads();
    // ---- one row per wave: dot(W_row, h) + dot(M_row, x) ----
    const float* hp = shh + (lane << 2);
    f4 h0 = *(const f4*)(hp);
    f4 h1 = *(const f4*)(hp + 256);
    f4 h2 = *(const f4*)(hp + 512);
    f4 h3 = *(const f4*)(hp + 768);
    f4 h4 = *(const f4*)(hp + 1024);
    f4 h5 = *(const f4*)(hp + 1280);
    f4 h6 = *(const f4*)(hp + 1536);
    f4 h7 = *(const f4*)(hp + 1792);
    float a = m * xv;
    a += w0.x * h0.x + w0.y * h0.y + w0.z * h0.z + w0.w * h0.w;
    a += w1.x * h1.x + w1.y * h1.y + w1.z * h1.z + w1.w * h1.w;
    a += w2.x * h2.x + w2.y * h2.y + w2.z * h2.z + w2.w * h2.w;
    a += w3.x * h3.x + w3.y * h3.y + w3.z * h3.z + w3.w * h3.w;
    a += w4.x * h4.x + w4.y * h4.y + w4.z * h4.z + w4.w * h4.w;
    a += w5.x * h5.x + w5.y * h5.y + w5.z * h5.z + w5.w * h5.w;
    a += w6.x * h6.x + w6.y * h6.y + w6.z * h6.z + w6.w * h6.w;
    a += w7.x * h7.x + w7.y * h7.y + w7.z * h7.z + w7.w * h7.w;
#pragma unroll
    for (int off = 32; off; off >>= 1) a += __shfl_xor(a, off, 64);
    if (lane == 0) {
      const float h = fast_tanh(a);
      u2 pv;
      pv.x = tg + 1u;
      pv.y = __float_as_uint(h);
      u2* dst = pairs + ((t & 1) << 11) + row;
      asm volatile("global_store_dwordx2 %0, %1, off sc0 sc1"
                   :: "v"(dst), "v"(pv) : "memory");
      ps[wave] = dwv * h;
    }
    __syncthreads();
    if (tid == 0) {
      float s = 0.f;
#pragma unroll
      for (int wv = 0; wv < 16; ++wv) s += ps[wv];
      yp[t * 128 + blockIdx.x] = s;
    }
  }
}

__global__ void esn_out(const float* __restrict__ X,
                        const float* __restrict__ wtil,
                        const float* __restrict__ yp,
                        const float* __restrict__ bptr,
                        float* __restrict__ out) {
  const int tid = threadIdx.x;
  const int lane = tid & 63;
  const int wave = tid >> 6;
  const int t = blockIdx.x * 4 + wave;
  float v = wtil[lane] * X[t * 64 + lane] + yp[t * 128 + lane] + yp[t * 128 + 64 + lane];
#pragma unroll
  for (int off = 32; off; off >>= 1) v += __shfl_xor(v, off, 64);
  if (lane == 0) out[t] = v + bptr[0];
}

extern "C" void kernel_launch(void* const* d_in, const int* in_sizes, int n_in,
                              void* d_out, int out_size, void* d_ws, size_t ws_size,
                              hipStream_t stream) {
  const float* X   = (const float*)d_in[0];
  const float* C   = (const float*)d_in[1];
  const float* Win = (const float*)d_in[2];
  const float* W   = (const float*)d_in[3];
  const float* dW  = (const float*)d_in[4];
  const float* db  = (const float*)d_in[5];
  float* ws   = (float*)d_ws;
  float* M    = ws;
  float* wtil = ws + 131072;
  float* yp   = ws + 131200;
  u2*    pairs = (u2*)(ws + 655488);

  esn_prep<<<2050, 64, 0, stream>>>(C, Win, dW, M, wtil, pairs);

  void* args[] = {(void*)&X, (void*)&M, (void*)&W, (void*)&dW,
                  (void*)&pairs, (void*)&yp};
  hipLaunchCooperativeKernel(reinterpret_cast<void*>(&esn_recur), dim3(128),
                             dim3(1024), args, 0, stream);

  esn_out<<<1024, 256, 0, stream>>>(X, wtil, yp, db, (float*)d_out);
}